// Round 1
// baseline (699.768 us; speedup 1.0000x reference)
//
#include <hip/hip_runtime.h>

#define NTOK 4096
#define NEXP 8
#define HD 2048
#define ID 1408

typedef unsigned short u16;
typedef __attribute__((ext_vector_type(8))) short short8;
typedef __attribute__((ext_vector_type(4))) float f32x4;
typedef const __attribute__((address_space(1))) void* gas_ptr;
typedef __attribute__((address_space(3))) void* las_ptr;

__device__ __forceinline__ u16 f2bf(float f) {
  unsigned int u = __float_as_uint(f);
  u += 0x7FFFu + ((u >> 16) & 1u);   // RNE
  return (u16)(u >> 16);
}

__device__ __forceinline__ void async16(const u16* g, u16* l) {
  __builtin_amdgcn_global_load_lds((gas_ptr)g, (las_ptr)l, 16, 0, 0);
}

// fp32 -> bf16 bulk convert, 8 elems/thread
__global__ void cvt_kernel(const float* __restrict__ s, u16* __restrict__ d, long n8) {
  long i = (long)blockIdx.x * blockDim.x + threadIdx.x;
  if (i >= n8) return;
  const float4* s4 = (const float4*)s;
  float4 a = s4[2*i], b = s4[2*i+1];
  short8 o;
  o[0] = (short)f2bf(a.x); o[1] = (short)f2bf(a.y);
  o[2] = (short)f2bf(a.z); o[3] = (short)f2bf(a.w);
  o[4] = (short)f2bf(b.x); o[5] = (short)f2bf(b.y);
  o[6] = (short)f2bf(b.z); o[7] = (short)f2bf(b.w);
  *(short8*)(d + 8*i) = o;
}

// router: logits (fp32), softmax, top-2, per-expert scatter lists
__global__ void router_kernel(const float* __restrict__ x, const float* __restrict__ gw,
                              float* __restrict__ logits, int* __restrict__ cnt,
                              int* __restrict__ ptok, float* __restrict__ pw) {
  int t = blockIdx.x * 4 + (threadIdx.x >> 6);   // one wave per token
  int lane = threadIdx.x & 63;
  if (t >= NTOK) return;
  const float4* xr = (const float4*)(x + (size_t)t * HD);
  float dot[NEXP];
#pragma unroll
  for (int e = 0; e < NEXP; ++e) dot[e] = 0.f;
#pragma unroll
  for (int c = 0; c < 8; ++c) {                  // 2048/4/64 = 8 chunks
    float4 xv = xr[c*64 + lane];
#pragma unroll
    for (int e = 0; e < NEXP; ++e) {
      float4 gv = ((const float4*)(gw + e*HD))[c*64 + lane];
      dot[e] += xv.x*gv.x + xv.y*gv.y + xv.z*gv.z + xv.w*gv.w;
    }
  }
#pragma unroll
  for (int off = 32; off > 0; off >>= 1) {
#pragma unroll
    for (int e = 0; e < NEXP; ++e) dot[e] += __shfl_xor(dot[e], off);
  }
  if (lane < NEXP) logits[(size_t)t*NEXP + lane] = dot[lane];
  if (lane == 0) {
    float mx = dot[0];
#pragma unroll
    for (int e = 1; e < NEXP; ++e) mx = fmaxf(mx, dot[e]);
    float p[NEXP];
#pragma unroll
    for (int e = 0; e < NEXP; ++e) p[e] = __expf(dot[e] - mx);
    int e0 = 0;
#pragma unroll
    for (int e = 1; e < NEXP; ++e) if (p[e] > p[e0]) e0 = e;   // ties -> lowest idx
    int e1 = (e0 == 0) ? 1 : 0;
#pragma unroll
    for (int e = 0; e < NEXP; ++e) if (e != e0 && p[e] > p[e1]) e1 = e;
    float denom = p[e0] + p[e1];
    int pos0 = atomicAdd(&cnt[e0], 1);
    ptok[e0*NTOK + pos0] = t; pw[e0*NTOK + pos0] = p[e0] / denom;
    int pos1 = atomicAdd(&cnt[e1], 1);
    ptok[e1*NTOK + pos1] = t; pw[e1*NTOK + pos1] = p[e1] / denom;
  }
}

__global__ void prefix_kernel(const int* __restrict__ cnt, int* __restrict__ offs) {
  if (threadIdx.x == 0) {
    int a = 0;
    for (int e = 0; e < NEXP; ++e) { offs[e] = a; a += cnt[e]; }
  }
}

// GEMM1: per expert, h = silu(x@wg^T) * (x@wu^T), rows gathered via ptok, h stored bf16
__global__ __launch_bounds__(256, 2) void gemm1_kernel(
    const u16* __restrict__ xb, const u16* __restrict__ wgb, const u16* __restrict__ wub,
    const int* __restrict__ cnt, const int* __restrict__ offs,
    const int* __restrict__ ptok, u16* __restrict__ hbuf) {
  int e = blockIdx.z, mt = blockIdx.y, nt = blockIdx.x;
  int c = cnt[e];
  if (mt * 128 >= c) return;
  int off = offs[e];

  __shared__ u16 sA[128*32], sBg[128*32], sBu[128*32];

  int tid = threadIdx.x;
  int r0 = tid >> 2;
  int ch = (tid & 3) * 8;
  int s0 = mt*128 + r0, s1 = s0 + 64;
  int t0 = ptok[e*NTOK + (s0 < c ? s0 : 0)];
  int t1 = ptok[e*NTOK + (s1 < c ? s1 : 0)];
  const u16* ga0 = xb + (size_t)t0*HD + ch;
  const u16* ga1 = xb + (size_t)t1*HD + ch;
  int n0 = nt*128 + r0;
  const u16* gg0 = wgb + ((size_t)e*ID + n0)*HD + ch;
  const u16* gg1 = gg0 + (size_t)64*HD;
  const u16* gu0 = wub + ((size_t)e*ID + n0)*HD + ch;
  const u16* gu1 = gu0 + (size_t)64*HD;

  int lane = tid & 63, wv = tid >> 6, wr = wv >> 1, wc = wv & 1;
  int fm = lane & 15, kg = lane >> 4;

  f32x4 accg[4][4], accu[4][4];
#pragma unroll
  for (int i = 0; i < 4; ++i)
#pragma unroll
    for (int j = 0; j < 4; ++j) {
      accg[i][j] = {0.f, 0.f, 0.f, 0.f};
      accu[i][j] = {0.f, 0.f, 0.f, 0.f};
    }

  const u16* sAf  = sA  + (wr*64 + fm)*32 + kg*8;
  const u16* sBgf = sBg + (wc*64 + fm)*32 + kg*8;
  const u16* sBuf = sBu + (wc*64 + fm)*32 + kg*8;

  for (int k0 = 0; k0 < HD; k0 += 32) {
    async16(ga0 + k0, sA + tid*8);
    async16(ga1 + k0, sA + 2048 + tid*8);
    async16(gg0 + k0, sBg + tid*8);
    async16(gg1 + k0, sBg + 2048 + tid*8);
    async16(gu0 + k0, sBu + tid*8);
    async16(gu1 + k0, sBu + 2048 + tid*8);
    __syncthreads();
    short8 af[4], bg[4], bu[4];
#pragma unroll
    for (int i = 0; i < 4; ++i) af[i] = *(const short8*)(sAf + i*512);
#pragma unroll
    for (int j = 0; j < 4; ++j) {
      bg[j] = *(const short8*)(sBgf + j*512);
      bu[j] = *(const short8*)(sBuf + j*512);
    }
#pragma unroll
    for (int i = 0; i < 4; ++i)
#pragma unroll
      for (int j = 0; j < 4; ++j) {
        accg[i][j] = __builtin_amdgcn_mfma_f32_16x16x32_bf16(af[i], bg[j], accg[i][j], 0, 0, 0);
        accu[i][j] = __builtin_amdgcn_mfma_f32_16x16x32_bf16(af[i], bu[j], accu[i][j], 0, 0, 0);
      }
    __syncthreads();
  }

#pragma unroll
  for (int i = 0; i < 4; ++i) {
#pragma unroll
    for (int r = 0; r < 4; ++r) {
      int slot = mt*128 + wr*64 + i*16 + kg*4 + r;
      if (slot < c) {
        size_t rowb = (size_t)(off + slot) * ID + nt*128 + wc*64 + fm;
#pragma unroll
        for (int j = 0; j < 4; ++j) {
          float g = accg[i][j][r], u = accu[i][j][r];
          float hh = g * u / (1.f + __expf(-g));   // silu(g)*u
          hbuf[rowb + (size_t)j*16] = f2bf(hh);
        }
      }
    }
  }
}

// GEMM2: y = h @ wd^T, weighted atomic scatter into out
__global__ __launch_bounds__(256, 2) void gemm2_kernel(
    const u16* __restrict__ hbuf, const u16* __restrict__ wdb,
    const int* __restrict__ cnt, const int* __restrict__ offs,
    const int* __restrict__ ptok, const float* __restrict__ pw,
    float* __restrict__ out) {
  int e = blockIdx.z, mt = blockIdx.y, nt = blockIdx.x;
  int c = cnt[e];
  if (mt * 128 >= c) return;
  int off = offs[e];

  __shared__ u16 sA[128*32], sB[128*32];

  int tid = threadIdx.x;
  int r0 = tid >> 2;
  int ch = (tid & 3) * 8;
  int s0 = mt*128 + r0, s1 = s0 + 64;
  const u16* ga0 = hbuf + (size_t)(off + (s0 < c ? s0 : 0))*ID + ch;
  const u16* ga1 = hbuf + (size_t)(off + (s1 < c ? s1 : 0))*ID + ch;
  int n0 = nt*128 + r0;
  const u16* gb0 = wdb + ((size_t)e*HD + n0)*ID + ch;
  const u16* gb1 = gb0 + (size_t)64*ID;

  int lane = tid & 63, wv = tid >> 6, wr = wv >> 1, wc = wv & 1;
  int fm = lane & 15, kg = lane >> 4;

  f32x4 acc[4][4];
#pragma unroll
  for (int i = 0; i < 4; ++i)
#pragma unroll
    for (int j = 0; j < 4; ++j) acc[i][j] = {0.f, 0.f, 0.f, 0.f};

  const u16* sAf = sA + (wr*64 + fm)*32 + kg*8;
  const u16* sBf = sB + (wc*64 + fm)*32 + kg*8;

  for (int k0 = 0; k0 < ID; k0 += 32) {
    async16(ga0 + k0, sA + tid*8);
    async16(ga1 + k0, sA + 2048 + tid*8);
    async16(gb0 + k0, sB + tid*8);
    async16(gb1 + k0, sB + 2048 + tid*8);
    __syncthreads();
    short8 af[4], bf[4];
#pragma unroll
    for (int i = 0; i < 4; ++i) af[i] = *(const short8*)(sAf + i*512);
#pragma unroll
    for (int j = 0; j < 4; ++j) bf[j] = *(const short8*)(sBf + j*512);
#pragma unroll
    for (int i = 0; i < 4; ++i)
#pragma unroll
      for (int j = 0; j < 4; ++j)
        acc[i][j] = __builtin_amdgcn_mfma_f32_16x16x32_bf16(af[i], bf[j], acc[i][j], 0, 0, 0);
    __syncthreads();
  }

#pragma unroll
  for (int i = 0; i < 4; ++i) {
#pragma unroll
    for (int r = 0; r < 4; ++r) {
      int slot = mt*128 + wr*64 + i*16 + kg*4 + r;
      if (slot < c) {
        int tok = ptok[e*NTOK + slot];
        float wgt = pw[e*NTOK + slot];
        float* orow = out + (size_t)tok*HD + nt*128 + wc*64 + fm;
#pragma unroll
        for (int j = 0; j < 4; ++j)
          atomicAdd(orow + j*16, wgt * acc[i][j][r]);
      }
    }
  }
}

extern "C" void kernel_launch(void* const* d_in, const int* in_sizes, int n_in,
                              void* d_out, int out_size, void* d_ws, size_t ws_size,
                              hipStream_t stream) {
  const float* x  = (const float*)d_in[0];
  const float* gw = (const float*)d_in[1];
  const float* wg = (const float*)d_in[2];
  const float* wu = (const float*)d_in[3];
  const float* wd = (const float*)d_in[4];
  float* out = (float*)d_out;

  // workspace carve (bytes), all 16B-aligned
  char* p = (char*)d_ws;
  u16*   xb   = (u16*)(p);                    //  16,777,216 B : x bf16 [4096,2048]
  u16*   wgb  = (u16*)(p + 16777216UL);       //  46,137,344 B : wg bf16
  u16*   wub  = (u16*)(p + 62914560UL);       //  46,137,344 B : wu bf16
  u16*   wdb  = (u16*)(p + 109051904UL);      //  46,137,344 B : wd bf16
  u16*   hbuf = (u16*)(p + 155189248UL);      //  23,068,672 B : h bf16 [8192,1408]
  int*   ptok = (int*)(p + 178257920UL);      //     131,072 B
  float* pww  = (float*)(p + 178388992UL);    //     131,072 B
  int*   cnt  = (int*)(p + 178520064UL);      //         256 B
  int*   offs = (int*)(p + 178520320UL);      //         256 B

  hipMemsetAsync(out, 0, (size_t)NTOK * HD * sizeof(float), stream);
  hipMemsetAsync(cnt, 0, NEXP * sizeof(int), stream);

  cvt_kernel<<<4096, 256, 0, stream>>>(x, xb, (long)NTOK * HD / 8);
  cvt_kernel<<<11264, 256, 0, stream>>>(wg, wgb, (long)NEXP * ID * HD / 8);
  cvt_kernel<<<11264, 256, 0, stream>>>(wu, wub, (long)NEXP * ID * HD / 8);
  cvt_kernel<<<11264, 256, 0, stream>>>(wd, wdb, (long)NEXP * HD * ID / 8);

  router_kernel<<<1024, 256, 0, stream>>>(x, gw, out + (size_t)NTOK * HD, cnt, ptok, pww);
  prefix_kernel<<<1, 64, 0, stream>>>(cnt, offs);

  gemm1_kernel<<<dim3(11, 32, 8), 256, 0, stream>>>(xb, wgb, wub, cnt, offs, ptok, hbuf);
  gemm2_kernel<<<dim3(16, 32, 8), 256, 0, stream>>>(hbuf, wdb, cnt, offs, ptok, pww, out);
}